// Round 6
// baseline (617.248 us; speedup 1.0000x reference)
//
#include <hip/hip_runtime.h>
#include <hip/hip_bf16.h>
#include <cstdint>
#include <cstddef>

typedef __bf16 bf16x8 __attribute__((ext_vector_type(8)));
typedef float  f32x4  __attribute__((ext_vector_type(4)));
typedef float  f32x16 __attribute__((ext_vector_type(16)));

typedef const __attribute__((address_space(1))) unsigned int gu32;
typedef __attribute__((address_space(3))) unsigned int lu32;

static __device__ __forceinline__ float bf2f(unsigned short u){
  unsigned v = ((unsigned)u) << 16;
  return __builtin_bit_cast(float, v);
}
static __device__ __forceinline__ unsigned short f2bf_bits(float f){
  __bf16 h = (__bf16)f;
  return __builtin_bit_cast(unsigned short, h);
}

// ---------------- K0a: build St[s][n] = (sum_e w(s->n)) / max(cnt[n],1) -------
__global__ __launch_bounds__(1024) void k_build_S(const int* __restrict__ ei,
                                                  const float* __restrict__ ea,
                                                  int E, float* __restrict__ St){
  __shared__ float Ssh[40000];
  __shared__ float csh[200];
  __shared__ int nzsh;
  const int t = threadIdx.x;
  if (t == 0) nzsh = 0;
  for (int i = t; i < 40000; i += 1024) Ssh[i] = 0.f;
  if (t < 200) csh[t] = 0.f;
  __syncthreads();
  if (t < 256){ if (ei[2*t + 1] != 0) atomicOr(&nzsh, 1); }
  __syncthreads();
  const int is64 = (nzsh == 0);
  for (int e = t; e < E; e += 1024){
    int s, d;
    if (is64){ s = ei[2*e]; d = ei[2*(E+e)]; }
    else     { s = ei[e];   d = ei[E+e];     }
    if ((unsigned)s < 200u && (unsigned)d < 200u){
      atomicAdd(&Ssh[s*200 + d], ea[e]);
      atomicAdd(&csh[d], 1.f);
    }
  }
  __syncthreads();
  for (int i = t; i < 40000; i += 1024){
    int n = i % 200;
    St[i] = Ssh[i] / fmaxf(csh[n], 1.f);
  }
}

// ---------------- K0b: x (f32) -> Xb (bf16, 256 rows, XOR-swizzled layout) ----
// byte(r,k) = r*32768 + (k/64)*128 + ((slot ^ (r&7))*16) + (k%8)*2, slot=(k%64)/8
__global__ __launch_bounds__(256) void k_xb(const float* __restrict__ x,
                                            unsigned char* __restrict__ Xb){
  int idx0 = blockIdx.x*256 + threadIdx.x;
  for (int idx = idx0; idx < 256*2048; idx += 256*256){
    int r  = idx >> 11;
    int sl = idx & 2047;
    int kc = sl >> 3, s = sl & 7;
    float4 v0 = {0.f,0.f,0.f,0.f}, v1 = {0.f,0.f,0.f,0.f};
    if (r < 200){
      const float* p = x + (size_t)r*16384 + kc*64 + s*8;
      v0 = *(const float4*)p;
      v1 = *(const float4*)(p + 4);
    }
    union { uint4 u; __bf16 h[8]; } pk;
    pk.h[0]=(__bf16)v0.x; pk.h[1]=(__bf16)v0.y; pk.h[2]=(__bf16)v0.z; pk.h[3]=(__bf16)v0.w;
    pk.h[4]=(__bf16)v1.x; pk.h[5]=(__bf16)v1.y; pk.h[6]=(__bf16)v1.z; pk.h[7]=(__bf16)v1.w;
    *(uint4*)(Xb + (size_t)r*32768 + kc*128 + ((s ^ (r & 7)) << 4)) = pk.u;
  }
}

// ---------------- GEMM: Cpart[ks][224][NOUT] = A(224 x K) * [Wl;Wr]^T ----------
// BN=32 cols/block, 32x32x16 MFMA, 4 waves (M-groups {2,2,2,1} tiles of 32 rows).
// B: global_load_lds, ONE instr = ONE 1KB contiguous run of a W row -> LDS
//    [col][k] f32 (1040B pad). DRAM gets 1KB/row-activate instead of 256B.
// A: global_load_lds from pre-swizzled source, BK_A=128, 2 buffers.
// Counted-vmcnt FIFO schedule; vm never drained to 0 in the main loop.
template<int KSPLIT, int KDIM, int NOUT, int NITER>
__global__ __launch_bounds__(256) void k_gemm(const unsigned char* __restrict__ Asrc,
                                              const float* __restrict__ Wl,
                                              const float* __restrict__ Wr,
                                              unsigned short* __restrict__ Cpart){
  constexpr int ROWB  = KDIM * 2;        // A row bytes (bf16)
  constexpr int NT2   = (NOUT/2) / 32;
  constexpr int BPAD  = 1040;            // B col pitch (1024 + 16 pad)
  constexpr int LOGKS = (KSPLIT == 2) ? 1 : 3;
  __shared__ unsigned char Abuf0[224*256];   // 57344: BK_A=128 sub-buffer
  __shared__ unsigned char Abuf1[224*256];
  __shared__ unsigned char Bl[32*BPAD];      // 33280

  const int tid  = threadIdx.x;
  const int lane = tid & 63, w = tid >> 6;
  const int bid  = blockIdx.x;
  const int ks    = bid & (KSPLIT - 1);      // XCD-constant (bid%8 fixed per XCD)
  const int ntile = bid >> LOGKS;
  const float* W = (ntile < NT2) ? (Wl + (size_t)ntile*32*KDIM)
                                 : (Wr + (size_t)(ntile - NT2)*32*KDIM);
  const int kb0   = ks * NITER;              // B-stage units of 256 k
  const int phase = ntile & (NITER - 1);
  auto kbAt = [&](int i){ return kb0 + ((i + phase) & (NITER - 1)); };

  // ---- B issue: 8 gload_lds/wave, each = 1KB contiguous run of one W row ----
  auto issueB = [&](int kb){
    #pragma unroll
    for (int jb = 0; jb < 8; jb++){
      int col = w*8 + jb;
      __builtin_amdgcn_global_load_lds(
          (gu32*)((const unsigned char*)W + (size_t)col*KDIM*4 + (size_t)kb*1024 + lane*16),
          (lu32*)(Bl + col*BPAD + lane*16), 16, 0, 0);
    }
    __builtin_amdgcn_sched_barrier(0);
  };

  // ---- A issue: 14 gload_lds/wave; src per-lane picks swizzled slot so LDS
  //      sub-buffer[row][d] holds k-window 8*(d ^ (row&7)). ----
  const int l4 = (lane >> 4) & 3, dd = lane & 15;
  const unsigned char* Aln = Asrc + (size_t)l4*ROWB + (dd >> 3)*128 + (dd & 7)*16;
  auto issueA = [&](unsigned char* buf, int cb){   // cb = 64k-chunk base
    #pragma unroll
    for (int j = 0; j < 14; j++){
      int jg = w*14 + j;
      __builtin_amdgcn_global_load_lds(
          (gu32*)(Aln + (size_t)jg*4*ROWB + (size_t)cb*128),
          (lu32*)(buf + jg*1024 + lane*16), 16, 0, 0);
    }
    __builtin_amdgcn_sched_barrier(0);
  };

  // ---- B fragment extraction (per stage: 16 frags = 64 VGPR) ----
  bf16x8 bf[2][8];
  const int kbase = (lane >> 5) << 3;        // 0 or 8
  const int bcol  = lane & 31;
  auto extractB = [&](){
    #pragma unroll
    for (int sub = 0; sub < 2; sub++)
      #pragma unroll
      for (int kst = 0; kst < 8; kst++){
        int k = sub*128 + kst*16 + kbase;
        const float* p = (const float*)(Bl + bcol*BPAD + k*4);
        float4 lo = *(const float4*)p;
        float4 hi = *(const float4*)(p + 4);
        bf16x8 v;
        v[0]=(__bf16)lo.x; v[1]=(__bf16)lo.y; v[2]=(__bf16)lo.z; v[3]=(__bf16)lo.w;
        v[4]=(__bf16)hi.x; v[5]=(__bf16)hi.y; v[6]=(__bf16)hi.z; v[7]=(__bf16)hi.w;
        bf[sub][kst] = v;
        if ((kst & 3) == 3) __builtin_amdgcn_sched_barrier(0);
      }
  };

  f32x16 acc[2];
  #pragma unroll
  for (int mt = 0; mt < 2; mt++)
    #pragma unroll
    for (int rr = 0; rr < 16; rr++) acc[mt][rr] = 0.f;

  const int arow_l = lane & 31;
  const int l7 = lane & 7;
  auto compute = [&](const unsigned char* buf, int sub){
    #pragma unroll
    for (int kst = 0; kst < 8; kst++){
      int s8x = (kst*2 + (lane >> 5));
      #pragma unroll
      for (int mt = 0; mt < 2; mt++){
        if (mt == 1 && w == 3) continue;           // wave 3 has 1 M-tile
        int row = (w*2 + mt)*32 + arow_l;
        bf16x8 af = *(const bf16x8*)(buf + row*256 + ((s8x ^ l7) << 4));
        acc[mt] = __builtin_amdgcn_mfma_f32_32x32x16_bf16(af, bf[sub][kst], acc[mt], 0, 0, 0);
      }
    }
  };

  // ---- prologue: stage 0's B + A(s0) in flight ----
  issueB(kbAt(0));
  issueA(Abuf0, kbAt(0)*4 + 0);

  for (int i = 0; i < NITER; i++){
    // queue: [B(i) 8][A(i,s0) 14] -> drain B(i) only
    asm volatile("s_waitcnt vmcnt(14)" ::: "memory");
    __builtin_amdgcn_s_barrier();
    __builtin_amdgcn_sched_barrier(0);
    extractB();
    asm volatile("s_waitcnt lgkmcnt(0)" ::: "memory");
    __builtin_amdgcn_s_barrier();                  // B-LDS free
    __builtin_amdgcn_sched_barrier(0);
    issueA(Abuf1, kbAt(i)*4 + 2);                  // s1
    issueB(kbAt(i + 1));                           // next stage B (wraps at end; harmless)
    // queue: [A s0 14][A s1 14][B' 8] -> drain A(s0) only
    asm volatile("s_waitcnt vmcnt(22)" ::: "memory");
    __builtin_amdgcn_sched_barrier(0);
    compute(Abuf0, 0);
    asm volatile("s_waitcnt lgkmcnt(0)" ::: "memory");
    __builtin_amdgcn_s_barrier();                  // Abuf0 free
    __builtin_amdgcn_sched_barrier(0);
    issueA(Abuf0, kbAt(i + 1)*4 + 0);              // next stage s0
    // queue: [A s1 14][B' 8][A' s0 14] -> drain A(s1) only
    asm volatile("s_waitcnt vmcnt(22)" ::: "memory");
    __builtin_amdgcn_sched_barrier(0);
    compute(Abuf1, 1);
  }

  // ---- epilogue: C layout col=lane&31, row=(rr&3)+8*(rr>>2)+4*(lane>>5) ----
  const int col = ntile*32 + (lane & 31);
  #pragma unroll
  for (int mt = 0; mt < 2; mt++){
    if (mt == 1 && w == 3) continue;
    #pragma unroll
    for (int rr = 0; rr < 16; rr++){
      int row = (w*2 + mt)*32 + (rr & 3) + 8*(rr >> 2) + 4*(lane >> 5);
      Cpart[(size_t)(ks*224 + row)*NOUT + col] = f2bf_bits(acc[mt][rr]);
    }
  }
}

// ---------------- reduce K partials (bf16) -> f32 ------------------------------
template<int KS>
__global__ __launch_bounds__(256) void k_reduce(const unsigned short* __restrict__ cp,
                                                float* __restrict__ out, int n8){
  const size_t part = (size_t)n8 * 8;
  int stride = gridDim.x * blockDim.x;
  for (int idx = blockIdx.x*blockDim.x + threadIdx.x; idx < n8; idx += stride){
    float a[8] = {0.f,0.f,0.f,0.f,0.f,0.f,0.f,0.f};
    #pragma unroll
    for (int ksi = 0; ksi < KS; ksi++){
      union { uint4 v; unsigned short s[8]; } u;
      u.v = *(const uint4*)(cp + ksi*part + (size_t)idx*8);
      #pragma unroll
      for (int j = 0; j < 8; j++) a[j] += bf2f(u.s[j]);
    }
    float4 lo = {a[0],a[1],a[2],a[3]};
    float4 hi = {a[4],a[5],a[6],a[7]};
    *(float4*)(out + (size_t)idx*8)     = lo;
    *(float4*)(out + (size_t)idx*8 + 4) = hi;
  }
}

// ---------------- h1 = relu(S@P + Q + b1) -> H1b (swizzled bf16) ---------------
__global__ __launch_bounds__(256) void k_h1(const float* __restrict__ PQ,
                                            const float* __restrict__ St,
                                            const float* __restrict__ b1,
                                            unsigned char* __restrict__ H1b){
  __shared__ float Ssh[200*50];
  const int och = blockIdx.x >> 2, nsp = blockIdx.x & 3;
  const int t = threadIdx.x;
  for (int i = t; i < 200*50; i += 256){
    int s = i / 50, j = i - s*50;
    Ssh[i] = St[s*200 + nsp*50 + j];
  }
  __syncthreads();
  const int w = t >> 6, lane = t & 63;
  const int o = och*64 + lane;
  const int jb = w*13;
  const int jn = (w == 3) ? 11 : 13;
  float acc[13];
  #pragma unroll
  for (int i = 0; i < 13; i++) acc[i] = 0.f;
  for (int s = 0; s < 200; s++){
    float p = PQ[(size_t)s*8192 + o];
    #pragma unroll
    for (int i = 0; i < 13; i++)
      if (i < jn) acc[i] = fmaf(Ssh[s*50 + jb + i], p, acc[i]);
  }
  float bo = b1[o];
  #pragma unroll
  for (int i = 0; i < 13; i++)
    if (i < jn){
      int r = nsp*50 + jb + i;
      float h = acc[i] + PQ[(size_t)r*8192 + 4096 + o] + bo;
      h = fmaxf(h, 0.f);
      int kc = o >> 6, wi = o & 63, slot = wi >> 3, rem = wi & 7;
      *(__bf16*)(H1b + (size_t)r*8192 + kc*128 + (((slot ^ (r & 7)) << 4) | (rem*2))) = (__bf16)h;
    }
}

// ---------------- h2 = S@R + T + b2 (no relu) ----------------------------------
__global__ __launch_bounds__(256) void k_h2(const float* __restrict__ RT,
                                            const float* __restrict__ St,
                                            const float* __restrict__ b2,
                                            float* __restrict__ h2){
  __shared__ float Ssh[200*13];
  const int cch = blockIdx.x >> 4, nsp = blockIdx.x & 15;
  const int nb0 = nsp * 13;
  const int t = threadIdx.x;
  for (int i = t; i < 200*13; i += 256){
    int s = i / 13, j = i - s*13;
    int g = nb0 + j;
    Ssh[i] = (g < 200) ? St[s*200 + g] : 0.f;
  }
  __syncthreads();
  const int w = t >> 6, lane = t & 63;
  const int c = cch*64 + lane;
  float acc[4] = {0.f, 0.f, 0.f, 0.f};
  for (int s = 0; s < 200; s++){
    float r = RT[(size_t)s*1024 + c];
    #pragma unroll
    for (int ii = 0; ii < 4; ii++){
      int j = w*4 + ii;
      if (j < 13 && nb0 + j < 200)
        acc[ii] = fmaf(Ssh[s*13 + j], r, acc[ii]);
    }
  }
  float bc = b2[c];
  #pragma unroll
  for (int ii = 0; ii < 4; ii++){
    int j = w*4 + ii;
    if (j < 13 && nb0 + j < 200){
      int n = nb0 + j;
      h2[(size_t)n*512 + c] = acc[ii] + RT[(size_t)n*1024 + 512 + c] + bc;
    }
  }
}

// ---------------- classifier: out[512,10] = mlp(h2^T) --------------------------
__global__ __launch_bounds__(512) void k_cls(const float* __restrict__ h2,
    const float* __restrict__ Wc1, const float* __restrict__ bc1,
    const float* __restrict__ Wc2, const float* __restrict__ bc2,
    const float* __restrict__ Wc3, const float* __restrict__ bc3,
    float* __restrict__ out){
  __shared__ float zt[64*201];
  __shared__ float z1[64*101];
  __shared__ float z2[64*51];
  const int cb = blockIdx.x * 64;
  const int t = threadIdx.x;
  for (int idx = t; idx < 64*200; idx += 512){
    int n = idx >> 6, cl = idx & 63;
    zt[cl*201 + n] = h2[(size_t)n*512 + cb + cl];
  }
  __syncthreads();
  const int w = t >> 6, c = t & 63;
  {
    const int jb = __builtin_amdgcn_readfirstlane(w*13);
    const int jn = (w == 7) ? 9 : 13;
    float a[13];
    #pragma unroll
    for (int j = 0; j < 13; j++) a[j] = (j < jn) ? bc1[jb + j] : 0.f;
    for (int n = 0; n < 200; n++){
      float v = zt[c*201 + n];
      #pragma unroll
      for (int j = 0; j < 13; j++)
        if (j < jn) a[j] = fmaf(v, Wc1[(jb + j)*200 + n], a[j]);
    }
    #pragma unroll
    for (int j = 0; j < 13; j++)
      if (j < jn) z1[c*101 + jb + j] = fmaxf(a[j], 0.f);
  }
  __syncthreads();
  {
    const int jb = __builtin_amdgcn_readfirstlane(w*7);
    const int jn = (w == 7) ? 1 : 7;
    float a[7];
    #pragma unroll
    for (int j = 0; j < 7; j++) a[j] = (j < jn) ? bc2[jb + j] : 0.f;
    for (int n = 0; n < 100; n++){
      float v = z1[c*101 + n];
      #pragma unroll
      for (int j = 0; j < 7; j++)
        if (j < jn) a[j] = fmaf(v, Wc2[(jb + j)*100 + n], a[j]);
    }
    #pragma unroll
    for (int j = 0; j < 7; j++)
      if (j < jn) z2[c*51 + jb + j] = fmaxf(a[j], 0.f);
  }
  __syncthreads();
  if (w < 5){
    const int jb = __builtin_amdgcn_readfirstlane(w*2);
    float a[2] = { bc3[jb], bc3[jb + 1] };
    for (int n = 0; n < 50; n++){
      float v = z2[c*51 + n];
      a[0] = fmaf(v, Wc3[jb*50 + n], a[0]);
      a[1] = fmaf(v, Wc3[(jb + 1)*50 + n], a[1]);
    }
    out[(size_t)(cb + c)*10 + jb]     = a[0];
    out[(size_t)(cb + c)*10 + jb + 1] = a[1];
  }
}

// ---------------- host launch ---------------------------------------------------
extern "C" void kernel_launch(void* const* d_in, const int* in_sizes, int n_in,
                              void* d_out, int out_size, void* d_ws, size_t ws_size,
                              hipStream_t stream){
  (void)n_in; (void)out_size; (void)ws_size;
  const float* x   = (const float*)d_in[0];
  const int*   ei  = (const int*)  d_in[1];
  const float* ea  = (const float*)d_in[2];
  const float* W1l = (const float*)d_in[3];
  const float* W1r = (const float*)d_in[4];
  const float* b1  = (const float*)d_in[5];
  const float* W2l = (const float*)d_in[6];
  const float* W2r = (const float*)d_in[7];
  const float* b2  = (const float*)d_in[8];
  const float* Wc1 = (const float*)d_in[9];
  const float* bc1 = (const float*)d_in[10];
  const float* Wc2 = (const float*)d_in[11];
  const float* bc2 = (const float*)d_in[12];
  const float* Wc3 = (const float*)d_in[13];
  const float* bc3 = (const float*)d_in[14];
  float* out = (float*)d_out;
  char* ws = (char*)d_ws;
  const int E = in_sizes[1] / 2;

  constexpr size_t ST_OFF  = 0;                                   // 160000
  constexpr size_t XB_OFF  = 262144;                              // 8 MiB
  constexpr size_t CP1_OFF = XB_OFF + (size_t)256*16384*2;        // 2 x 224 x 8192 bf16
  constexpr size_t PQ_OFF  = CP1_OFF + (size_t)2*224*8192*2;      // 224 x 8192 f32
  constexpr size_t H1B_OFF = PQ_OFF + (size_t)224*8192*4;         // 256 x 4096 bf16
  constexpr size_t CP2_OFF = H1B_OFF + (size_t)256*4096*2;        // 8 x 224 x 1024 bf16
  constexpr size_t RT_OFF  = CP2_OFF + (size_t)8*224*1024*2;      // 224 x 1024 f32
  constexpr size_t H2_OFF  = RT_OFF + (size_t)224*1024*4;         // 200 x 512 f32

  float*          St  = (float*)(ws + ST_OFF);
  unsigned char*  Xb  = (unsigned char*)(ws + XB_OFF);
  unsigned short* Cp1 = (unsigned short*)(ws + CP1_OFF);
  float*          PQ  = (float*)(ws + PQ_OFF);
  unsigned char*  H1b = (unsigned char*)(ws + H1B_OFF);
  unsigned short* Cp2 = (unsigned short*)(ws + CP2_OFF);
  float*          RT  = (float*)(ws + RT_OFF);
  float*          h2  = (float*)(ws + H2_OFF);

  k_build_S<<<dim3(1),   dim3(1024), 0, stream>>>(ei, ea, E, St);
  k_xb     <<<dim3(256), dim3(256),  0, stream>>>(x, Xb);
  k_gemm<2, 16384, 8192, 32><<<dim3(512), dim3(256), 0, stream>>>(Xb, W1l, W1r, Cp1);
  k_reduce<2> <<<dim3(256), dim3(256), 0, stream>>>(Cp1, PQ, 224*8192/8);
  k_h1     <<<dim3(256), dim3(256),  0, stream>>>(PQ, St, b1, H1b);
  k_gemm<8, 4096, 1024, 2><<<dim3(256), dim3(256), 0, stream>>>(H1b, W2l, W2r, Cp2);
  k_reduce<8> <<<dim3(64), dim3(256), 0, stream>>>(Cp2, RT, 224*1024/8);
  k_h2     <<<dim3(128), dim3(256),  0, stream>>>(RT, St, b2, h2);
  k_cls    <<<dim3(8),   dim3(512),  0, stream>>>(h2, Wc1, bc1, Wc2, bc2, Wc3, bc3, out);
}

// Round 7
// 599.759 us; speedup vs baseline: 1.0292x; 1.0292x over previous
//
#include <hip/hip_runtime.h>
#include <hip/hip_bf16.h>
#include <cstdint>
#include <cstddef>

typedef __bf16 bf16x8 __attribute__((ext_vector_type(8)));
typedef float  f32x4  __attribute__((ext_vector_type(4)));

static __device__ __forceinline__ float bf2f(unsigned short u){
  unsigned v = ((unsigned)u) << 16;
  return __builtin_bit_cast(float, v);
}
static __device__ __forceinline__ unsigned short f2bf_bits(float f){
  __bf16 h = (__bf16)f;
  return __builtin_bit_cast(unsigned short, h);
}

// ---------------- K0a: build St[s][n] = (sum_e w(s->n)) / max(cnt[n],1) -------
__global__ __launch_bounds__(1024) void k_build_S(const int* __restrict__ ei,
                                                  const float* __restrict__ ea,
                                                  int E, float* __restrict__ St){
  __shared__ float Ssh[40000];
  __shared__ float csh[200];
  __shared__ int nzsh;
  const int t = threadIdx.x;
  if (t == 0) nzsh = 0;
  for (int i = t; i < 40000; i += 1024) Ssh[i] = 0.f;
  if (t < 200) csh[t] = 0.f;
  __syncthreads();
  if (t < 256){ if (ei[2*t + 1] != 0) atomicOr(&nzsh, 1); }
  __syncthreads();
  const int is64 = (nzsh == 0);
  for (int e = t; e < E; e += 1024){
    int s, d;
    if (is64){ s = ei[2*e]; d = ei[2*(E+e)]; }
    else     { s = ei[e];   d = ei[E+e];     }
    if ((unsigned)s < 200u && (unsigned)d < 200u){
      atomicAdd(&Ssh[s*200 + d], ea[e]);
      atomicAdd(&csh[d], 1.f);
    }
  }
  __syncthreads();
  for (int i = t; i < 40000; i += 1024){
    int n = i % 200;
    St[i] = Ssh[i] / fmaxf(csh[n], 1.f);
  }
}

// ---------------- K0b: x (f32) -> Xfrag (fragment-major bf16) ------------------
// Xfrag chunk idx = (mt*512 + kc)*64 + lane, 16B each:
//   holds A[mt*16 + (lane&15)][kc*32 + (lane>>4)*8 .. +8] as bf16x8 (0 for row>=200)
__global__ __launch_bounds__(256) void k_xb(const float* __restrict__ x,
                                            unsigned char* __restrict__ Xf){
  int idx = blockIdx.x*256 + threadIdx.x;          // 14*512*64 = 458752 total
  if (idx >= 14*512*64) return;
  int lane = idx & 63;
  int kc   = (idx >> 6) & 511;
  int mt   = idx >> 15;
  int row  = mt*16 + (lane & 15);
  int k    = kc*32 + (lane >> 4)*8;
  float4 v0 = {0.f,0.f,0.f,0.f}, v1 = {0.f,0.f,0.f,0.f};
  if (row < 200){
    const float* p = x + (size_t)row*16384 + k;
    v0 = *(const float4*)p;
    v1 = *(const float4*)(p + 4);
  }
  union { uint4 u; __bf16 h[8]; } pk;
  pk.h[0]=(__bf16)v0.x; pk.h[1]=(__bf16)v0.y; pk.h[2]=(__bf16)v0.z; pk.h[3]=(__bf16)v0.w;
  pk.h[4]=(__bf16)v1.x; pk.h[5]=(__bf16)v1.y; pk.h[6]=(__bf16)v1.z; pk.h[7]=(__bf16)v1.w;
  *(uint4*)(Xf + (size_t)idx*16) = pk.u;
}

// ---------------- GEMM: Cpart[ks][224][NOUT] = A(224 x K) * [Wl;Wr]^T ----------
// 1 wave per block, NO LDS, NO barriers. Wave owns 32 cols x 224 rows x k-slice.
// A: fragment-major global buffer -> bf16x8 regs directly (1KB coalesced, L2-hit).
// B: W f32 -> regs -> cvt. Free-running waves give per-CU TLP for HBM latency.
template<int KDIM, int NOUT, int KS>
__global__ __launch_bounds__(64) void k_gemm(const unsigned char* __restrict__ Afrag,
                                             const float* __restrict__ Wl,
                                             const float* __restrict__ Wr,
                                             unsigned short* __restrict__ Cpart){
  constexpr int KCH = KDIM / 32;          // total k-chunks
  constexpr int NST = KCH / KS;           // stages per block (even)
  constexpr int NT2 = (NOUT/2) / 32;
  const int lane = threadIdx.x & 63;
  const int l15  = lane & 15, lk = lane >> 4;
  const int bid  = blockIdx.x;
  const int ks    = bid & (KS - 1);       // bid%8 == ks%8 -> XCD-aligned A slice
  const int ntile = bid / KS;
  const float* W = (ntile < NT2) ? (Wl + (size_t)ntile*32*KDIM)
                                 : (Wr + (size_t)(ntile - NT2)*32*KDIM);
  const int kc0 = ks * NST;

  const float* B0 = W + (size_t)l15*KDIM + lk*8 + (size_t)kc0*32;
  const float* B1 = B0 + (size_t)16*KDIM;
  const unsigned char* AB = Afrag + ((size_t)kc0 + (size_t)0)*1024 + lane*16;

  f32x4 acc[14][2];
  #pragma unroll
  for (int mt = 0; mt < 14; mt++){ acc[mt][0] = (f32x4){0,0,0,0}; acc[mt][1] = (f32x4){0,0,0,0}; }

  float4 bA[4], bB[4];
  auto loadB = [&](float4* b, int st){
    const float* p0 = B0 + (size_t)st*32;
    b[0] = *(const float4*)p0; b[1] = *(const float4*)(p0 + 4);
    const float* p1 = B1 + (size_t)st*32;
    b[2] = *(const float4*)p1; b[3] = *(const float4*)(p1 + 4);
  };
  auto mkfrag = [&](const float4* b, bf16x8* f0, bf16x8* f1){
    bf16x8 v0, v1;
    v0[0]=(__bf16)b[0].x; v0[1]=(__bf16)b[0].y; v0[2]=(__bf16)b[0].z; v0[3]=(__bf16)b[0].w;
    v0[4]=(__bf16)b[1].x; v0[5]=(__bf16)b[1].y; v0[6]=(__bf16)b[1].z; v0[7]=(__bf16)b[1].w;
    v1[0]=(__bf16)b[2].x; v1[1]=(__bf16)b[2].y; v1[2]=(__bf16)b[2].z; v1[3]=(__bf16)b[2].w;
    v1[4]=(__bf16)b[3].x; v1[5]=(__bf16)b[3].y; v1[6]=(__bf16)b[3].z; v1[7]=(__bf16)b[3].w;
    *f0 = v0; *f1 = v1;
  };
  auto stage = [&](const float4* b, int st){
    bf16x8 bf0, bf1;
    mkfrag(b, &bf0, &bf1);
    #pragma unroll
    for (int mt = 0; mt < 14; mt++){
      bf16x8 af = *(const bf16x8*)(AB + ((size_t)mt*KCH + st)*1024);
      acc[mt][0] = __builtin_amdgcn_mfma_f32_16x16x32_bf16(af, bf0, acc[mt][0], 0, 0, 0);
      acc[mt][1] = __builtin_amdgcn_mfma_f32_16x16x32_bf16(af, bf1, acc[mt][1], 0, 0, 0);
    }
  };

  loadB(bA, 0);
  for (int st = 0; st < NST; st += 2){
    if (st + 1 < NST) loadB(bB, st + 1);
    stage(bA, st);
    if (st + 2 < NST) loadB(bA, st + 2);
    stage(bB, st + 1);
  }

  // epilogue: C 16x16 layout col=lane&15, row=(lane>>4)*4+j
  const int cb = ntile*32;
  #pragma unroll
  for (int mt = 0; mt < 14; mt++)
    #pragma unroll
    for (int ns = 0; ns < 2; ns++)
      #pragma unroll
      for (int j = 0; j < 4; j++){
        int row = mt*16 + lk*4 + j;
        int col = cb + ns*16 + l15;
        Cpart[(size_t)(ks*224 + row)*NOUT + col] = f2bf_bits(acc[mt][ns][j]);
      }
}

// ---------------- reduce K partials (bf16) -> f32 ------------------------------
template<int KS>
__global__ __launch_bounds__(256) void k_reduce(const unsigned short* __restrict__ cp,
                                                float* __restrict__ out, int n8){
  const size_t part = (size_t)n8 * 8;
  int stride = gridDim.x * blockDim.x;
  for (int idx = blockIdx.x*blockDim.x + threadIdx.x; idx < n8; idx += stride){
    float a[8] = {0.f,0.f,0.f,0.f,0.f,0.f,0.f,0.f};
    #pragma unroll
    for (int ksi = 0; ksi < KS; ksi++){
      union { uint4 v; unsigned short s[8]; } u;
      u.v = *(const uint4*)(cp + ksi*part + (size_t)idx*8);
      #pragma unroll
      for (int j = 0; j < 8; j++) a[j] += bf2f(u.s[j]);
    }
    float4 lo = {a[0],a[1],a[2],a[3]};
    float4 hi = {a[4],a[5],a[6],a[7]};
    *(float4*)(out + (size_t)idx*8)     = lo;
    *(float4*)(out + (size_t)idx*8 + 4) = hi;
  }
}

// ---------------- h1 = relu(S@P + Q + b1) -> H1f (fragment-major bf16) ---------
// H1f byte(r,o) = ((r>>4)*128 + (o>>5))*1024 + (((o>>3)&3)*16 + (r&15))*16 + (o&7)*2
__global__ __launch_bounds__(256) void k_h1(const float* __restrict__ PQ,
                                            const float* __restrict__ St,
                                            const float* __restrict__ b1,
                                            unsigned char* __restrict__ H1f){
  __shared__ float Ssh[200*50];
  const int och = blockIdx.x >> 2, nsp = blockIdx.x & 3;
  const int t = threadIdx.x;
  for (int i = t; i < 200*50; i += 256){
    int s = i / 50, j = i - s*50;
    Ssh[i] = St[s*200 + nsp*50 + j];
  }
  __syncthreads();
  const int w = t >> 6, lane = t & 63;
  const int o = och*64 + lane;
  const int jb = w*13;
  const int jn = (w == 3) ? 11 : 13;
  float acc[13];
  #pragma unroll
  for (int i = 0; i < 13; i++) acc[i] = 0.f;
  for (int s = 0; s < 200; s++){
    float p = PQ[(size_t)s*8192 + o];
    #pragma unroll
    for (int i = 0; i < 13; i++)
      if (i < jn) acc[i] = fmaf(Ssh[s*50 + jb + i], p, acc[i]);
  }
  float bo = b1[o];
  const int kc = o >> 5, lkk = (o >> 3) & 3, jj = o & 7;
  #pragma unroll
  for (int i = 0; i < 13; i++)
    if (i < jn){
      int r = nsp*50 + jb + i;
      float h = acc[i] + PQ[(size_t)r*8192 + 4096 + o] + bo;
      h = fmaxf(h, 0.f);
      size_t off = (((size_t)(r >> 4)*128 + kc) << 10) + (size_t)(lkk*16 + (r & 15))*16 + jj*2;
      *(__bf16*)(H1f + off) = (__bf16)h;
    }
}

// ---------------- zero H1f slots for rows 200..223 -----------------------------
__global__ __launch_bounds__(256) void k_ztail(unsigned char* __restrict__ H1f){
  // i over [24 rows][4 lk][128 kc]
  for (int i = threadIdx.x; i < 24*4*128; i += 256){
    int kc = i & 127;
    int lkk = (i >> 7) & 3;
    int r  = 200 + (i >> 9);
    int mt = r >> 4;
    int lane = lkk*16 + (r & 15);
    uint4 z = {0,0,0,0};
    *(uint4*)(H1f + (((size_t)mt*128 + kc) << 10) + lane*16) = z;
  }
}

// ---------------- h2 = S@R + T + b2 (no relu) ----------------------------------
__global__ __launch_bounds__(256) void k_h2(const float* __restrict__ RT,
                                            const float* __restrict__ St,
                                            const float* __restrict__ b2,
                                            float* __restrict__ h2){
  __shared__ float Ssh[200*13];
  const int cch = blockIdx.x >> 4, nsp = blockIdx.x & 15;
  const int nb0 = nsp * 13;
  const int t = threadIdx.x;
  for (int i = t; i < 200*13; i += 256){
    int s = i / 13, j = i - s*13;
    int g = nb0 + j;
    Ssh[i] = (g < 200) ? St[s*200 + g] : 0.f;
  }
  __syncthreads();
  const int w = t >> 6, lane = t & 63;
  const int c = cch*64 + lane;
  float acc[4] = {0.f, 0.f, 0.f, 0.f};
  for (int s = 0; s < 200; s++){
    float r = RT[(size_t)s*1024 + c];
    #pragma unroll
    for (int ii = 0; ii < 4; ii++){
      int j = w*4 + ii;
      if (j < 13 && nb0 + j < 200)
        acc[ii] = fmaf(Ssh[s*13 + j], r, acc[ii]);
    }
  }
  float bc = b2[c];
  #pragma unroll
  for (int ii = 0; ii < 4; ii++){
    int j = w*4 + ii;
    if (j < 13 && nb0 + j < 200){
      int n = nb0 + j;
      h2[(size_t)n*512 + c] = acc[ii] + RT[(size_t)n*1024 + 512 + c] + bc;
    }
  }
}

// ---------------- classifier: out[512,10] = mlp(h2^T) --------------------------
__global__ __launch_bounds__(512) void k_cls(const float* __restrict__ h2,
    const float* __restrict__ Wc1, const float* __restrict__ bc1,
    const float* __restrict__ Wc2, const float* __restrict__ bc2,
    const float* __restrict__ Wc3, const float* __restrict__ bc3,
    float* __restrict__ out){
  __shared__ float zt[64*201];
  __shared__ float z1[64*101];
  __shared__ float z2[64*51];
  const int cb = blockIdx.x * 64;
  const int t = threadIdx.x;
  for (int idx = t; idx < 64*200; idx += 512){
    int n = idx >> 6, cl = idx & 63;
    zt[cl*201 + n] = h2[(size_t)n*512 + cb + cl];
  }
  __syncthreads();
  const int w = t >> 6, c = t & 63;
  {
    const int jb = __builtin_amdgcn_readfirstlane(w*13);
    const int jn = (w == 7) ? 9 : 13;
    float a[13];
    #pragma unroll
    for (int j = 0; j < 13; j++) a[j] = (j < jn) ? bc1[jb + j] : 0.f;
    for (int n = 0; n < 200; n++){
      float v = zt[c*201 + n];
      #pragma unroll
      for (int j = 0; j < 13; j++)
        if (j < jn) a[j] = fmaf(v, Wc1[(jb + j)*200 + n], a[j]);
    }
    #pragma unroll
    for (int j = 0; j < 13; j++)
      if (j < jn) z1[c*101 + jb + j] = fmaxf(a[j], 0.f);
  }
  __syncthreads();
  {
    const int jb = __builtin_amdgcn_readfirstlane(w*7);
    const int jn = (w == 7) ? 1 : 7;
    float a[7];
    #pragma unroll
    for (int j = 0; j < 7; j++) a[j] = (j < jn) ? bc2[jb + j] : 0.f;
    for (int n = 0; n < 100; n++){
      float v = z1[c*101 + n];
      #pragma unroll
      for (int j = 0; j < 7; j++)
        if (j < jn) a[j] = fmaf(v, Wc2[(jb + j)*100 + n], a[j]);
    }
    #pragma unroll
    for (int j = 0; j < 7; j++)
      if (j < jn) z2[c*51 + jb + j] = fmaxf(a[j], 0.f);
  }
  __syncthreads();
  if (w < 5){
    const int jb = __builtin_amdgcn_readfirstlane(w*2);
    float a[2] = { bc3[jb], bc3[jb + 1] };
    for (int n = 0; n < 50; n++){
      float v = z2[c*51 + n];
      a[0] = fmaf(v, Wc3[jb*50 + n], a[0]);
      a[1] = fmaf(v, Wc3[(jb + 1)*50 + n], a[1]);
    }
    out[(size_t)(cb + c)*10 + jb]     = a[0];
    out[(size_t)(cb + c)*10 + jb + 1] = a[1];
  }
}

// ---------------- host launch ---------------------------------------------------
extern "C" void kernel_launch(void* const* d_in, const int* in_sizes, int n_in,
                              void* d_out, int out_size, void* d_ws, size_t ws_size,
                              hipStream_t stream){
  (void)n_in; (void)out_size; (void)ws_size;
  const float* x   = (const float*)d_in[0];
  const int*   ei  = (const int*)  d_in[1];
  const float* ea  = (const float*)d_in[2];
  const float* W1l = (const float*)d_in[3];
  const float* W1r = (const float*)d_in[4];
  const float* b1  = (const float*)d_in[5];
  const float* W2l = (const float*)d_in[6];
  const float* W2r = (const float*)d_in[7];
  const float* b2  = (const float*)d_in[8];
  const float* Wc1 = (const float*)d_in[9];
  const float* bc1 = (const float*)d_in[10];
  const float* Wc2 = (const float*)d_in[11];
  const float* bc2 = (const float*)d_in[12];
  const float* Wc3 = (const float*)d_in[13];
  const float* bc3 = (const float*)d_in[14];
  float* out = (float*)d_out;
  char* ws = (char*)d_ws;
  const int E = in_sizes[1] / 2;

  constexpr size_t ST_OFF  = 0;                                   // 160000
  constexpr size_t XF_OFF  = 262144;                              // 14*512*1024 = 7.34 MB
  constexpr size_t CP1_OFF = XF_OFF + (size_t)14*512*1024;        // 8 x 224 x 8192 bf16
  constexpr size_t PQ_OFF  = CP1_OFF + (size_t)8*224*8192*2;      // 224 x 8192 f32
  constexpr size_t H1F_OFF = PQ_OFF + (size_t)224*8192*4;         // 14*128*1024 = 1.84 MB
  constexpr size_t CP2_OFF = H1F_OFF + (size_t)14*128*1024;       // 32 x 224 x 1024 bf16
  constexpr size_t RT_OFF  = CP2_OFF + (size_t)32*224*1024*2;     // 224 x 1024 f32
  constexpr size_t H2_OFF  = RT_OFF + (size_t)224*1024*4;         // 200 x 512 f32

  float*          St  = (float*)(ws + ST_OFF);
  unsigned char*  Xf  = (unsigned char*)(ws + XF_OFF);
  unsigned short* Cp1 = (unsigned short*)(ws + CP1_OFF);
  float*          PQ  = (float*)(ws + PQ_OFF);
  unsigned char*  H1f = (unsigned char*)(ws + H1F_OFF);
  unsigned short* Cp2 = (unsigned short*)(ws + CP2_OFF);
  float*          RT  = (float*)(ws + RT_OFF);
  float*          h2  = (float*)(ws + H2_OFF);

  k_xb     <<<dim3(1792), dim3(256),  0, stream>>>(x, Xf);
  k_build_S<<<dim3(1),    dim3(1024), 0, stream>>>(ei, ea, E, St);
  k_gemm<16384, 8192, 8><<<dim3(2048), dim3(64), 0, stream>>>(Xf, W1l, W1r, Cp1);
  k_reduce<8> <<<dim3(256), dim3(256), 0, stream>>>(Cp1, PQ, 224*8192/8);
  k_h1     <<<dim3(256),  dim3(256),  0, stream>>>(PQ, St, b1, H1f);
  k_ztail  <<<dim3(1),    dim3(256),  0, stream>>>(H1f);
  k_gemm<4096, 1024, 32><<<dim3(1024), dim3(64), 0, stream>>>(H1f, W2l, W2r, Cp2);
  k_reduce<32><<<dim3(112), dim3(256), 0, stream>>>(Cp2, RT, 224*1024/8);
  k_h2     <<<dim3(128),  dim3(256),  0, stream>>>(RT, St, b2, h2);
  k_cls    <<<dim3(8),    dim3(512),  0, stream>>>(h2, Wc1, bc1, Wc2, bc2, Wc3, bc3, out);
}

// Round 8
// 467.179 us; speedup vs baseline: 1.3212x; 1.2838x over previous
//
#include <hip/hip_runtime.h>
#include <hip/hip_bf16.h>
#include <cstdint>
#include <cstddef>

typedef __bf16 bf16x8 __attribute__((ext_vector_type(8)));
typedef float  f32x4  __attribute__((ext_vector_type(4)));

typedef const __attribute__((address_space(1))) unsigned int gu32;
typedef __attribute__((address_space(3))) unsigned int lu32;

static __device__ __forceinline__ float bf2f(unsigned short u){
  unsigned v = ((unsigned)u) << 16;
  return __builtin_bit_cast(float, v);
}
static __device__ __forceinline__ unsigned short f2bf_bits(float f){
  __bf16 h = (__bf16)f;
  return __builtin_bit_cast(unsigned short, h);
}

// ---------------- K0a: build St[s][n] = (sum_e w(s->n)) / max(cnt[n],1) -------
__global__ __launch_bounds__(1024) void k_build_S(const int* __restrict__ ei,
                                                  const float* __restrict__ ea,
                                                  int E, float* __restrict__ St){
  __shared__ float Ssh[40000];
  __shared__ float csh[200];
  __shared__ int nzsh;
  const int t = threadIdx.x;
  if (t == 0) nzsh = 0;
  for (int i = t; i < 40000; i += 1024) Ssh[i] = 0.f;
  if (t < 200) csh[t] = 0.f;
  __syncthreads();
  if (t < 256){ if (ei[2*t + 1] != 0) atomicOr(&nzsh, 1); }
  __syncthreads();
  const int is64 = (nzsh == 0);
  for (int e = t; e < E; e += 1024){
    int s, d;
    if (is64){ s = ei[2*e]; d = ei[2*(E+e)]; }
    else     { s = ei[e];   d = ei[E+e];     }
    if ((unsigned)s < 200u && (unsigned)d < 200u){
      atomicAdd(&Ssh[s*200 + d], ea[e]);
      atomicAdd(&csh[d], 1.f);
    }
  }
  __syncthreads();
  for (int i = t; i < 40000; i += 1024){
    int n = i % 200;
    St[i] = Ssh[i] / fmaxf(csh[n], 1.f);
  }
}

// ---------------- K0b: x (f32) -> Xb (bf16, 256 rows, XOR-swizzled layout) ----
// byte(r,k) = r*32768 + (k/64)*128 + ((slot ^ (r&7))*16) + (k%8)*2, slot=(k%64)/8
__global__ __launch_bounds__(256) void k_xb(const float* __restrict__ x,
                                            unsigned char* __restrict__ Xb){
  int idx0 = blockIdx.x*256 + threadIdx.x;
  for (int idx = idx0; idx < 256*2048; idx += 256*256){
    int r  = idx >> 11;
    int sl = idx & 2047;
    int kc = sl >> 3, s = sl & 7;
    float4 v0 = {0.f,0.f,0.f,0.f}, v1 = {0.f,0.f,0.f,0.f};
    if (r < 200){
      const float* p = x + (size_t)r*16384 + kc*64 + s*8;
      v0 = *(const float4*)p;
      v1 = *(const float4*)(p + 4);
    }
    union { uint4 u; __bf16 h[8]; } pk;
    pk.h[0]=(__bf16)v0.x; pk.h[1]=(__bf16)v0.y; pk.h[2]=(__bf16)v0.z; pk.h[3]=(__bf16)v0.w;
    pk.h[4]=(__bf16)v1.x; pk.h[5]=(__bf16)v1.y; pk.h[6]=(__bf16)v1.z; pk.h[7]=(__bf16)v1.w;
    *(uint4*)(Xb + (size_t)r*32768 + kc*128 + ((s ^ (r & 7)) << 4)) = pk.u;
  }
}

// ---------------- GEMM: Cpart[ks][224][NOUT] = A(224 x K) * [Wl;Wr]^T ----------
// BN=128, BK=64, 4 waves, wave owns 32 cols x 224 rows (acc[14][2]).
// B: f32 -> regs, DOUBLE-buffered (2 stages in flight). A: global_load_lds
// (pre-swizzled source), LDS double buffer 2x28KB.
// Counted vmcnt: stage-top waits vmcnt(15) = [B(i+1):8 + A(i+1):7] younger ops
// stay in flight -> the vm queue NEVER drains during the 32-stage loop.
template<int BN, int KSPLIT, int KDIM, int NOUT, int NITER>
__global__ __launch_bounds__(256, 2) void k_gemm(const unsigned char* __restrict__ Asrc,
                                                 const float* __restrict__ Wl,
                                                 const float* __restrict__ Wr,
                                                 unsigned short* __restrict__ Cpart){
  constexpr int ROWB = KDIM * 2;
  constexpr int NT   = NOUT / BN;
  constexpr int NT2  = (NOUT/2) / BN;
  constexpr int NS   = BN / 64;            // 16-col strips per wave (=2)
  constexpr int NB   = NS * 2 * 2;         // float4 staging per set (=8)
  __shared__ unsigned char Lds[2][224*128];

  const int tid  = threadIdx.x;
  const int lane = tid & 63, wid = tid >> 6;
  const int l15  = lane & 15, lk = lane >> 4;
  const int bid  = blockIdx.x;
  const int ks    = bid & (KSPLIT - 1);    // ks%8 = XCD id -> A slice L2-resident
  const int ntile = bid / KSPLIT;
  const float* W = (ntile < NT2) ? (Wl + (size_t)ntile*BN*KDIM)
                                 : (Wr + (size_t)(ntile - NT2)*BN*KDIM);
  const int kc0   = ks * NITER;
  const int phase = ntile & (NITER - 1);
  auto kcAt = [&](int i){ return kc0 + ((i + phase) & (NITER - 1)); };

  const float* WB = W + (size_t)(wid*32 + l15)*KDIM + lk*8;
  float4 b0[NB], b1[NB];

  auto issueB = [&](float4 (&b)[NB], int kc){
    const float* p = WB + (size_t)kc*64;
    #pragma unroll
    for (int ns = 0; ns < NS; ns++)
      #pragma unroll
      for (int kst = 0; kst < 2; kst++){
        const float* q = p + (size_t)ns*16*KDIM + kst*32;
        b[(ns*2+kst)*2 + 0] = *(const float4*)q;
        b[(ns*2+kst)*2 + 1] = *(const float4*)(q + 4);
      }
    __builtin_amdgcn_sched_barrier(0);
  };

  const unsigned char* AG = Asrc + (size_t)(tid >> 3)*ROWB + (tid & 7)*16;
  auto issueA = [&](unsigned char* buf, int kc){
    const unsigned char* g = AG + (size_t)kc*128;
    #pragma unroll
    for (int j = 0; j < 7; j++){
      __builtin_amdgcn_global_load_lds(
          (gu32*)(g + (size_t)j*32*ROWB),
          (lu32*)(buf + j*4096 + wid*1024),
          16, 0, 0);
    }
    __builtin_amdgcn_sched_barrier(0);
  };

  bf16x8 frag[NS*2];
  auto cvtB = [&](const float4 (&b)[NB]){
    #pragma unroll
    for (int f = 0; f < NS*2; f++){
      float4 lo = b[f*2], hi = b[f*2+1];
      bf16x8 v;
      v[0]=(__bf16)lo.x; v[1]=(__bf16)lo.y; v[2]=(__bf16)lo.z; v[3]=(__bf16)lo.w;
      v[4]=(__bf16)hi.x; v[5]=(__bf16)hi.y; v[6]=(__bf16)hi.z; v[7]=(__bf16)hi.w;
      frag[f] = v;
    }
  };

  f32x4 acc[14][NS];
  #pragma unroll
  for (int mt = 0; mt < 14; mt++)
    #pragma unroll
    for (int ns = 0; ns < NS; ns++)
      acc[mt][ns] = (f32x4){0.f,0.f,0.f,0.f};

  auto compute = [&](const unsigned char* buf){
    #pragma unroll
    for (int kst = 0; kst < 2; kst++){
      const int sx = (((kst*4 + lk) ^ (l15 & 7)) << 4);
      #pragma unroll
      for (int mt = 0; mt < 14; mt++){
        bf16x8 af = *(const bf16x8*)(buf + (mt*16 + l15)*128 + sx);
        #pragma unroll
        for (int ns = 0; ns < NS; ns++)
          acc[mt][ns] = __builtin_amdgcn_mfma_f32_16x16x32_bf16(af, frag[ns*2+kst], acc[mt][ns], 0, 0, 0);
      }
    }
  };

  // one pipeline stage; bc/Lc bound at compile time via hand-unroll x2
  auto STAGE = [&](float4 (&bc)[NB], unsigned char* Lc, int i){
    if (i + 1 < NITER) asm volatile("s_waitcnt vmcnt(15) lgkmcnt(0)" ::: "memory");
    else               asm volatile("s_waitcnt vmcnt(0) lgkmcnt(0)" ::: "memory");
    __builtin_amdgcn_s_barrier();
    __builtin_amdgcn_sched_barrier(0);
    cvtB(bc);                                  // frees bc
    if (i + 2 < NITER) issueB(bc, kcAt(i + 2));
    __builtin_amdgcn_sched_barrier(0);
    compute(Lc);
    __builtin_amdgcn_s_barrier();              // all waves done reading Lc
    __builtin_amdgcn_sched_barrier(0);
    if (i + 2 < NITER) issueA(Lc, kcAt(i + 2));
  };

  // prologue: queue = [B0 A0 B1 A1]
  issueB(b0, kcAt(0)); issueA(Lds[0], kcAt(0));
  issueB(b1, kcAt(1)); issueA(Lds[1], kcAt(1));

  for (int i = 0; i < NITER; i += 2){          // NITER even
    STAGE(b0, Lds[0], i);
    STAGE(b1, Lds[1], i + 1);
  }

  // epilogue: bf16 partial store
  const int rbase = ks * 224;
  const int cbase = ntile*BN + wid*32;
  #pragma unroll
  for (int mt = 0; mt < 14; mt++)
    #pragma unroll
    for (int ns = 0; ns < NS; ns++)
      #pragma unroll
      for (int j = 0; j < 4; j++){
        int row = mt*16 + lk*4 + j;
        int col = cbase + ns*16 + l15;
        Cpart[(size_t)(rbase + row)*NOUT + col] = f2bf_bits(acc[mt][ns][j]);
      }
}

// ---------------- reduce K partials (bf16) -> f32 ------------------------------
template<int KS>
__global__ __launch_bounds__(256) void k_reduce(const unsigned short* __restrict__ cp,
                                                float* __restrict__ out, int n8){
  const size_t part = (size_t)n8 * 8;
  int stride = gridDim.x * blockDim.x;
  for (int idx = blockIdx.x*blockDim.x + threadIdx.x; idx < n8; idx += stride){
    float a[8] = {0.f,0.f,0.f,0.f,0.f,0.f,0.f,0.f};
    #pragma unroll
    for (int ksi = 0; ksi < KS; ksi++){
      union { uint4 v; unsigned short s[8]; } u;
      u.v = *(const uint4*)(cp + ksi*part + (size_t)idx*8);
      #pragma unroll
      for (int j = 0; j < 8; j++) a[j] += bf2f(u.s[j]);
    }
    float4 lo = {a[0],a[1],a[2],a[3]};
    float4 hi = {a[4],a[5],a[6],a[7]};
    *(float4*)(out + (size_t)idx*8)     = lo;
    *(float4*)(out + (size_t)idx*8 + 4) = hi;
  }
}

// ---------------- h1 = relu(S@P + Q + b1) -> H1b (swizzled bf16) ---------------
__global__ __launch_bounds__(256) void k_h1(const float* __restrict__ PQ,
                                            const float* __restrict__ St,
                                            const float* __restrict__ b1,
                                            unsigned char* __restrict__ H1b){
  __shared__ float Ssh[200*50];
  const int och = blockIdx.x >> 2, nsp = blockIdx.x & 3;
  const int t = threadIdx.x;
  for (int i = t; i < 200*50; i += 256){
    int s = i / 50, j = i - s*50;
    Ssh[i] = St[s*200 + nsp*50 + j];
  }
  __syncthreads();
  const int w = t >> 6, lane = t & 63;
  const int o = och*64 + lane;
  const int jb = w*13;
  const int jn = (w == 3) ? 11 : 13;
  float acc[13];
  #pragma unroll
  for (int i = 0; i < 13; i++) acc[i] = 0.f;
  for (int s = 0; s < 200; s++){
    float p = PQ[(size_t)s*8192 + o];
    #pragma unroll
    for (int i = 0; i < 13; i++)
      if (i < jn) acc[i] = fmaf(Ssh[s*50 + jb + i], p, acc[i]);
  }
  float bo = b1[o];
  #pragma unroll
  for (int i = 0; i < 13; i++)
    if (i < jn){
      int r = nsp*50 + jb + i;
      float h = acc[i] + PQ[(size_t)r*8192 + 4096 + o] + bo;
      h = fmaxf(h, 0.f);
      int kc = o >> 6, wi = o & 63, slot = wi >> 3, rem = wi & 7;
      *(__bf16*)(H1b + (size_t)r*8192 + kc*128 + (((slot ^ (r & 7)) << 4) | (rem*2))) = (__bf16)h;
    }
}

// ---------------- h2 = S@R + T + b2 (no relu) ----------------------------------
__global__ __launch_bounds__(256) void k_h2(const float* __restrict__ RT,
                                            const float* __restrict__ St,
                                            const float* __restrict__ b2,
                                            float* __restrict__ h2){
  __shared__ float Ssh[200*13];
  const int cch = blockIdx.x >> 4, nsp = blockIdx.x & 15;
  const int nb0 = nsp * 13;
  const int t = threadIdx.x;
  for (int i = t; i < 200*13; i += 256){
    int s = i / 13, j = i - s*13;
    int g = nb0 + j;
    Ssh[i] = (g < 200) ? St[s*200 + g] : 0.f;
  }
  __syncthreads();
  const int w = t >> 6, lane = t & 63;
  const int c = cch*64 + lane;
  float acc[4] = {0.f, 0.f, 0.f, 0.f};
  for (int s = 0; s < 200; s++){
    float r = RT[(size_t)s*1024 + c];
    #pragma unroll
    for (int ii = 0; ii < 4; ii++){
      int j = w*4 + ii;
      if (j < 13 && nb0 + j < 200)
        acc[ii] = fmaf(Ssh[s*13 + j], r, acc[ii]);
    }
  }
  float bc = b2[c];
  #pragma unroll
  for (int ii = 0; ii < 4; ii++){
    int j = w*4 + ii;
    if (j < 13 && nb0 + j < 200){
      int n = nb0 + j;
      h2[(size_t)n*512 + c] = acc[ii] + RT[(size_t)n*1024 + 512 + c] + bc;
    }
  }
}

// ---------------- classifier: out[512,10] = mlp(h2^T) --------------------------
__global__ __launch_bounds__(512) void k_cls(const float* __restrict__ h2,
    const float* __restrict__ Wc1, const float* __restrict__ bc1,
    const float* __restrict__ Wc2, const float* __restrict__ bc2,
    const float* __restrict__ Wc3, const float* __restrict__ bc3,
    float* __restrict__ out){
  __shared__ float zt[64*201];
  __shared__ float z1[64*101];
  __shared__ float z2[64*51];
  const int cb = blockIdx.x * 64;
  const int t = threadIdx.x;
  for (int idx = t; idx < 64*200; idx += 512){
    int n = idx >> 6, cl = idx & 63;
    zt[cl*201 + n] = h2[(size_t)n*512 + cb + cl];
  }
  __syncthreads();
  const int w = t >> 6, c = t & 63;
  {
    const int jb = __builtin_amdgcn_readfirstlane(w*13);
    const int jn = (w == 7) ? 9 : 13;
    float a[13];
    #pragma unroll
    for (int j = 0; j < 13; j++) a[j] = (j < jn) ? bc1[jb + j] : 0.f;
    for (int n = 0; n < 200; n++){
      float v = zt[c*201 + n];
      #pragma unroll
      for (int j = 0; j < 13; j++)
        if (j < jn) a[j] = fmaf(v, Wc1[(jb + j)*200 + n], a[j]);
    }
    #pragma unroll
    for (int j = 0; j < 13; j++)
      if (j < jn) z1[c*101 + jb + j] = fmaxf(a[j], 0.f);
  }
  __syncthreads();
  {
    const int jb = __builtin_amdgcn_readfirstlane(w*7);
    const int jn = (w == 7) ? 1 : 7;
    float a[7];
    #pragma unroll
    for (int j = 0; j < 7; j++) a[j] = (j < jn) ? bc2[jb + j] : 0.f;
    for (int n = 0; n < 100; n++){
      float v = z1[c*101 + n];
      #pragma unroll
      for (int j = 0; j < 7; j++)
        if (j < jn) a[j] = fmaf(v, Wc2[(jb + j)*100 + n], a[j]);
    }
    #pragma unroll
    for (int j = 0; j < 7; j++)
      if (j < jn) z2[c*51 + jb + j] = fmaxf(a[j], 0.f);
  }
  __syncthreads();
  if (w < 5){
    const int jb = __builtin_amdgcn_readfirstlane(w*2);
    float a[2] = { bc3[jb], bc3[jb + 1] };
    for (int n = 0; n < 50; n++){
      float v = z2[c*51 + n];
      a[0] = fmaf(v, Wc3[jb*50 + n], a[0]);
      a[1] = fmaf(v, Wc3[(jb + 1)*50 + n], a[1]);
    }
    out[(size_t)(cb + c)*10 + jb]     = a[0];
    out[(size_t)(cb + c)*10 + jb + 1] = a[1];
  }
}

// ---------------- host launch ---------------------------------------------------
extern "C" void kernel_launch(void* const* d_in, const int* in_sizes, int n_in,
                              void* d_out, int out_size, void* d_ws, size_t ws_size,
                              hipStream_t stream){
  (void)n_in; (void)out_size; (void)ws_size;
  const float* x   = (const float*)d_in[0];
  const int*   ei  = (const int*)  d_in[1];
  const float* ea  = (const float*)d_in[2];
  const float* W1l = (const float*)d_in[3];
  const float* W1r = (const float*)d_in[4];
  const float* b1  = (const float*)d_in[5];
  const float* W2l = (const float*)d_in[6];
  const float* W2r = (const float*)d_in[7];
  const float* b2  = (const float*)d_in[8];
  const float* Wc1 = (const float*)d_in[9];
  const float* bc1 = (const float*)d_in[10];
  const float* Wc2 = (const float*)d_in[11];
  const float* bc2 = (const float*)d_in[12];
  const float* Wc3 = (const float*)d_in[13];
  const float* bc3 = (const float*)d_in[14];
  float* out = (float*)d_out;
  char* ws = (char*)d_ws;
  const int E = in_sizes[1] / 2;

  constexpr size_t ST_OFF  = 0;                                   // 160000
  constexpr size_t XB_OFF  = 262144;                              // 8 MiB
  constexpr size_t CP1_OFF = XB_OFF + (size_t)256*16384*2;        // 8 x 224 x 8192 bf16
  constexpr size_t PQ_OFF  = CP1_OFF + (size_t)8*224*8192*2;      // 224 x 8192 f32
  constexpr size_t H1B_OFF = PQ_OFF + (size_t)224*8192*4;         // 256 x 4096 bf16
  constexpr size_t CP2_OFF = H1B_OFF + (size_t)256*4096*2;        // 32 x 224 x 1024 bf16
  constexpr size_t RT_OFF  = CP2_OFF + (size_t)32*224*1024*2;     // 224 x 1024 f32
  constexpr size_t H2_OFF  = RT_OFF + (size_t)224*1024*4;         // 200 x 512 f32

  float*          St  = (float*)(ws + ST_OFF);
  unsigned char*  Xb  = (unsigned char*)(ws + XB_OFF);
  unsigned short* Cp1 = (unsigned short*)(ws + CP1_OFF);
  float*          PQ  = (float*)(ws + PQ_OFF);
  unsigned char*  H1b = (unsigned char*)(ws + H1B_OFF);
  unsigned short* Cp2 = (unsigned short*)(ws + CP2_OFF);
  float*          RT  = (float*)(ws + RT_OFF);
  float*          h2  = (float*)(ws + H2_OFF);

  k_build_S<<<dim3(1),   dim3(1024), 0, stream>>>(ei, ea, E, St);
  k_xb     <<<dim3(256), dim3(256),  0, stream>>>(x, Xb);
  // GEMM1: BN=128, KS=8, NITER = 16384/64/8 = 32, grid = 64*8 = 512 (2 blocks/CU)
  k_gemm<128, 8, 16384, 8192, 32><<<dim3(512), dim3(256), 0, stream>>>(Xb, W1l, W1r, Cp1);
  k_reduce<8> <<<dim3(256), dim3(256), 0, stream>>>(Cp1, PQ, 224*8192/8);
  k_h1     <<<dim3(256), dim3(256),  0, stream>>>(PQ, St, b1, H1b);
  // GEMM2: BN=128, KS=32, NITER = 4096/64/32 = 2, grid = 8*32 = 256
  k_gemm<128, 32, 4096, 1024, 2><<<dim3(256), dim3(256), 0, stream>>>(H1b, W2l, W2r, Cp2);
  k_reduce<32><<<dim3(64), dim3(256), 0, stream>>>(Cp2, RT, 224*1024/8);
  k_h2     <<<dim3(128), dim3(256),  0, stream>>>(RT, St, b2, h2);
  k_cls    <<<dim3(8),   dim3(512),  0, stream>>>(h2, Wc1, bc1, Wc2, bc2, Wc3, bc3, out);
}